// Round 1
// 1329.971 us; speedup vs baseline: 1.0212x; 1.0212x over previous
//
#include <hip/hip_runtime.h>

// Segmented sum: values (1048576, 256) fp32, segment_ids sorted (1048576,) int32,
// out (512, 256) fp32. Memory-bound: 1.074 GB read -> ~176 us floor @ 6.3 TB/s.
//
// v2: segment-aligned blocks. Block b owns quarter (b&3) of segment (b>>2),
// located via two wave-uniform 20-step binary searches on the sorted ids
// (TOTAL_POINTS = 2^20 exactly). This removes the per-row id-check slow path
// (previously ~25% of chunks, latency-chained and un-pipelineable) -- every
// block is now a branch-free unrolled streaming sum with one atomic flush.
// Segment sizes are 2048 +/- 45 (multinomial), so quarters are 512 +/- 11 rows:
// better load balance than fixed 512-row chunks. Plain (cached) loads instead
// of nontemporal: streaming 1.07 GB >> L3 anyway, and plain float4 loads are
// the measured 6.29 TB/s path.

#define TOTAL_POINTS 1048576
#define NCOLS 256
#define NSEGS 512
#define SPLIT 4                       // blocks per segment
#define NBLOCKS (NSEGS * SPLIT)       // 2048 = 8 blocks/CU, all co-resident

typedef float v4 __attribute__((ext_vector_type(4)));

__global__ __launch_bounds__(256) void segsum_kernel(
    const v4* __restrict__ vals,       // (TOTAL_POINTS, 64) as float4
    const int* __restrict__ segids,    // (TOTAL_POINTS,) sorted ascending
    float* __restrict__ out)           // (NSEGS, 256), pre-zeroed
{
    const int c4 = threadIdx.x & 63;   // float4 column index 0..63 (lane id)
    const int rg = threadIdx.x >> 6;   // wave id 0..3
    const int seg = blockIdx.x >> 2;
    const int q   = blockIdx.x & 3;

    // Two interleaved lower_bound searches (first idx with id >= seg / seg+1).
    // All operands are wave-uniform -> scalar/broadcast loads, no divergence.
    int lo0 = 0, hi0 = TOTAL_POINTS;
    int lo1 = 0, hi1 = TOTAL_POINTS;
    #pragma unroll
    for (int it = 0; it < 20; ++it) {
        const int m0 = (lo0 + hi0) >> 1;
        const int m1 = (lo1 + hi1) >> 1;
        const int a = segids[m0];
        const int b = segids[m1];
        if (a < seg)     lo0 = m0 + 1; else hi0 = m0;
        if (b < seg + 1) lo1 = m1 + 1; else hi1 = m1;
    }
    const int rows   = lo1 - lo0;               // rows in this segment
    const int rstart = lo0 + ((rows * q) >> 2);         // quarter [rstart, rend)
    const int rend   = lo0 + ((rows * (q + 1)) >> 2);

    // Wave rg streams rows rstart+rg, rstart+rg+4, ...
    const int n = rend - (rstart + rg);
    const int iters = (n > 0) ? ((n + 3) >> 2) : 0;

    v4 acc = (v4)(0.f);
    const v4* p = vals + (long)(rstart + rg) * 64 + c4;
    #pragma unroll 8
    for (int i = 0; i < iters; ++i) {
        acc += p[0];
        p += 4 * 64;                   // stride 4 rows
    }

    if (iters > 0) {
        float* o = out + (long)seg * NCOLS + (c4 << 2);
        atomicAdd(o + 0, acc.x);
        atomicAdd(o + 1, acc.y);
        atomicAdd(o + 2, acc.z);
        atomicAdd(o + 3, acc.w);
    }
}

extern "C" void kernel_launch(void* const* d_in, const int* in_sizes, int n_in,
                              void* d_out, int out_size, void* d_ws, size_t ws_size,
                              hipStream_t stream) {
    const float* vals = (const float*)d_in[0];
    const int* segids = (const int*)d_in[1];
    float* out = (float*)d_out;

    // Harness re-poisons d_out to 0xAA before every timed replay; zero it
    // ourselves (graph-capturable memset node). Also covers empty segments.
    hipMemsetAsync(out, 0, (size_t)out_size * sizeof(float), stream);

    segsum_kernel<<<NBLOCKS, 256, 0, stream>>>(
        (const v4*)vals, segids, out);
}

// Round 2
// 1315.304 us; speedup vs baseline: 1.0326x; 1.0112x over previous
//
#include <hip/hip_runtime.h>

// Segmented sum: values (1048576, 256) fp32, segment_ids sorted (1048576,) int32,
// out (512, 256) fp32. Memory-bound: 1.074 GB read -> ~176 us floor @ 6.3 TB/s.
//
// v3: zero atomics. One 1024-thread block per segment (512 blocks = 2/CU,
// 16 waves/block = full 32 waves/CU). Segment bounds via two wave-uniform
// 20-step binary searches (TOTAL_POINTS = 2^20). Each wave streams rows
// w, w+16, ... of its segment (block covers a contiguous region), reduces
// across waves in LDS, wave 0 writes each output element ONCE with a plain
// dwordx4 store. This removes the 2M contended device-scope fp32 atomicAdds
// (16 same-address RMWs per output element) that v1/v2 shared -- the prime
// suspect for both landing at ~1.7 TB/s effective read BW. Also drops the
// output memset: every element is written unconditionally (empty segment -> 0).

#define TOTAL_POINTS 1048576
#define NCOLS 256
#define NSEGS 512
#define NWAVES 16
#define BLOCK (NWAVES * 64)           // 1024

typedef float v4 __attribute__((ext_vector_type(4)));

__global__ __launch_bounds__(BLOCK) void segsum_kernel(
    const v4* __restrict__ vals,       // (TOTAL_POINTS, 64) as float4
    const int* __restrict__ segids,    // (TOTAL_POINTS,) sorted ascending
    float* __restrict__ out)           // (NSEGS, 256)
{
    const int c4 = threadIdx.x & 63;   // float4 column index 0..63 (lane id)
    const int w  = threadIdx.x >> 6;   // wave id 0..15
    const int seg = blockIdx.x;

    // Two interleaved lower_bound searches (first idx with id >= seg / seg+1).
    // Wave-uniform addresses -> broadcast loads, no divergence.
    int lo0 = 0, hi0 = TOTAL_POINTS;
    int lo1 = 0, hi1 = TOTAL_POINTS;
    #pragma unroll
    for (int it = 0; it < 20; ++it) {
        const int m0 = (lo0 + hi0) >> 1;
        const int m1 = (lo1 + hi1) >> 1;
        const int a = segids[m0];
        const int b = segids[m1];
        if (a < seg)     lo0 = m0 + 1; else hi0 = m0;
        if (b < seg + 1) lo1 = m1 + 1; else hi1 = m1;
    }
    const int rows = lo1 - lo0;        // rows in this segment (2048 +/- ~45)

    // Wave w streams rows lo0+w, lo0+w+16, ... : block region is contiguous.
    const int n = rows - w;
    const int iters = (n > 0) ? ((n + NWAVES - 1) >> 4) : 0;

    v4 acc = (v4)(0.f);
    const v4* p = vals + (long)(lo0 + w) * 64 + c4;
    #pragma unroll 8
    for (int i = 0; i < iters; ++i) {
        acc += p[0];
        p += NWAVES * 64;              // stride 16 rows
    }

    // Cross-wave reduction in LDS (16 KB), then one plain store per element.
    __shared__ v4 red[NWAVES][64];
    red[w][c4] = acc;
    __syncthreads();
    if (w == 0) {
        #pragma unroll
        for (int j = 1; j < NWAVES; ++j)
            acc += red[j][c4];         // ds_read_b128, conflict-free (contig 16B/lane)
        *((v4*)(out + (long)seg * NCOLS) + c4) = acc;
    }
}

extern "C" void kernel_launch(void* const* d_in, const int* in_sizes, int n_in,
                              void* d_out, int out_size, void* d_ws, size_t ws_size,
                              hipStream_t stream) {
    const float* vals = (const float*)d_in[0];
    const int* segids = (const int*)d_in[1];
    float* out = (float*)d_out;

    // No memset needed: every output element is written exactly once by the
    // kernel (rows == 0 stores zeros), so the harness's 0xAA poison is fully
    // overwritten.
    segsum_kernel<<<NSEGS, BLOCK, 0, stream>>>(
        (const v4*)vals, segids, out);
}